// Round 13
// baseline (3696.780 us; speedup 1.0000x reference)
//
#include <hip/hip_runtime.h>

typedef _Float16 f16x8 __attribute__((ext_vector_type(8)));
typedef _Float16 f16x4 __attribute__((ext_vector_type(4)));
typedef float    f32x4 __attribute__((ext_vector_type(4)));

typedef const __attribute__((address_space(1))) void* gptr_t;
typedef __attribute__((address_space(3))) void* lptr_t;

__device__ __forceinline__ void gload_lds16(const void* g, void* l) {
  __builtin_amdgcn_global_load_lds((gptr_t)g, (lptr_t)l, 16, 0, 0);
}

constexpr int Bsz  = 8192;
constexpr int Nin  = 128;
constexpr int Hd   = 1024;
constexpr int Aact = 32;
constexpr int Od   = 64;
constexpr int KC = 384;           // OpenBLAS K-block (R10-validated)
constexpr float DELTA = 2e-5f;    // borderline window (R10-validated)
constexpr unsigned WCAP = 65536;

// ---- digit split + swizzle into MFMA B-fragment order.
// w = d1 + d2*2^-12 + d3*2^-24 + r, |r|<=2^-36; digits are m*2^-11, exact f16;
// fp32 MFMA accumulation exact (sums << 2^24 in 2^-11 units).
// Layout: tile (nb = n/64, kb = k/32) -> 2048 f16 at (nb*(K/32)+kb)*2048,
// within tile [j][lane][e]: n = nb*64 + j*16 + (lane&15), k = kb*32 + (lane>>4)*8 + e.
// => gemm fragment read lB + j*512 + lane*8 is 64-lane contiguous: 0 bank conflicts.
__global__ void wsplit_tiled_kernel(const float* __restrict__ src,  // [k][n] row-major
                                    _Float16* __restrict__ d1, _Float16* __restrict__ d2,
                                    _Float16* __restrict__ d3, int N, int K) {
  const int tid = threadIdx.x;
  const int j = tid >> 6, lane = tid & 63, l15 = lane & 15, quad = lane >> 4;
  const int n = blockIdx.x * 64 + j * 16 + l15;
  const int kb = blockIdx.y;
  const int k0 = kb * 32 + quad * 8;
  f16x8 o1, o2, o3;
#pragma unroll
  for (int e = 0; e < 8; ++e) {
    float w = src[(size_t)(k0 + e) * N + n];
    float m1 = rintf(w * 2048.0f);
    float q1 = m1 * (1.0f / 2048.0f);
    float r  = w - q1;                       // exact
    float m2 = rintf(r * 8388608.0f);        // 2^23
    float q2 = m2 * (1.0f / 8388608.0f);
    float r2 = r - q2;                       // exact
    float m3 = rintf(r2 * 34359738368.0f);   // 2^35
    o1[e] = (_Float16)q1;
    o2[e] = (_Float16)(m2 * (1.0f / 2048.0f));
    o3[e] = (_Float16)(m3 * (1.0f / 2048.0f));
  }
  size_t off = ((size_t)blockIdx.x * (K / 32) + kb) * 2048 + (j * 64 + lane) * 8;
  *(f16x8*)(d1 + off) = o1;
  *(f16x8*)(d2 + off) = o2;
  *(f16x8*)(d3 + off) = o3;
}

// ---- fp32 transpose: src[R][C] -> dst[C][R] (fixup column contiguity)
__global__ void transpose_f32_kernel(const float* __restrict__ src,
                                     float* __restrict__ dst, int R, int C) {
  __shared__ float tile[32][33];
  int c0 = blockIdx.x * 32, r0 = blockIdx.y * 32;
  for (int i = threadIdx.y; i < 32; i += 8)
    tile[i][threadIdx.x] = src[(size_t)(r0 + i) * C + c0 + threadIdx.x];
  __syncthreads();
  for (int i = threadIdx.y; i < 32; i += 8)
    dst[(size_t)(c0 + i) * R + r0 + threadIdx.x] = tile[threadIdx.x][i];
}

// ---- layer 1: EMULATE np's sgemm (K=128 single block, ascending fp32 FMA),
// then the fp32 trajectory; v resets to exact 0 -> pack 8 steps' spikes/byte.
__global__ __launch_bounds__(256)
void x1_kernel(const float* __restrict__ state, const float* __restrict__ w1,
               const float* __restrict__ b1, unsigned char* __restrict__ s1pack) {
  __shared__ float sA[64][129];
  __shared__ float sB[128][32];
  const int m0 = blockIdx.x * 64, n0 = blockIdx.y * 32;
  const int tid = threadIdx.x;
  for (int idx = tid; idx < 64 * 32; idx += 256) {
    int r = idx >> 5, c4 = (idx & 31) << 2;
    float4 v = *(const float4*)(state + (size_t)(m0 + r) * Nin + c4);
    sA[r][c4] = v.x; sA[r][c4 + 1] = v.y; sA[r][c4 + 2] = v.z; sA[r][c4 + 3] = v.w;
  }
  for (int idx = tid; idx < 128 * 8; idx += 256) {
    int r = idx >> 3, c4 = (idx & 7) << 2;
    *(float4*)&sB[r][c4] = *(const float4*)(w1 + (size_t)r * Hd + n0 + c4);
  }
  __syncthreads();
  const int tx = tid & 15, ty = tid >> 4;
  float acc[4][2] = {};
  for (int k = 0; k < 128; ++k) {           // ASCENDING, single acc: np order
    float a[4], b[2];
#pragma unroll
    for (int i = 0; i < 4; ++i) a[i] = sA[ty * 4 + i][k];
#pragma unroll
    for (int j = 0; j < 2; ++j) b[j] = sB[k][tx * 2 + j];
#pragma unroll
    for (int i = 0; i < 4; ++i)
#pragma unroll
      for (int j = 0; j < 2; ++j) acc[i][j] = __fmaf_rn(a[i], b[j], acc[i][j]);
  }
#pragma unroll
  for (int i = 0; i < 4; ++i)
#pragma unroll
    for (int j = 0; j < 2; ++j) {
      int m = m0 + ty * 4 + i, n = n0 + tx * 2 + j;
      float x = acc[i][j];
      float bb = b1[n];
      float v = 0.0f;
      unsigned bits = 0;
#pragma unroll
      for (int t = 0; t < 8; ++t) {
        float h = __fadd_rn(__fadd_rn(v, x), bb);   // np: (v1 + G1) + b1
        if (h >= 1.0f) { bits |= (1u << t); v = 0.0f; } else { v = h; }
      }
      s1pack[(size_t)m * Hd + n] = (unsigned char)bits;
    }
}

// f16 A-fragment from 8 spike bytes (bit t) — values identical to f16 expand.
__device__ __forceinline__ f16x8 frag_from_bits(const unsigned char* ap, int t) {
  unsigned d0 = *(const unsigned*)ap;
  unsigned d1 = *(const unsigned*)(ap + 4);
  f16x8 a;
  a[0] = (_Float16)((d0 >> t) & 1u);
  a[1] = (_Float16)((d0 >> (8 + t)) & 1u);
  a[2] = (_Float16)((d0 >> (16 + t)) & 1u);
  a[3] = (_Float16)((d0 >> (24 + t)) & 1u);
  a[4] = (_Float16)((d1 >> t) & 1u);
  a[5] = (_Float16)((d1 >> (8 + t)) & 1u);
  a[6] = (_Float16)((d1 >> (16 + t)) & 1u);
  a[7] = (_Float16)((d1 >> (24 + t)) & 1u);
  return a;
}

// f16 A-fragment from 8 s2 bytes (each 0 or 1)
__device__ __forceinline__ f16x8 frag_from_bytes(const unsigned char* ap) {
  f16x8 a;
#pragma unroll
  for (int e = 0; e < 8; ++e) a[e] = (_Float16)(float)ap[e];
  return a;
}

// ---- GEMM2: exact 3-digit MFMA decides non-borderline spikes (== np);
// borderline -> worklist for fixup. B in fragment-order tiles (0 conflicts).
// s2 written as bytes per t (consumed by batched gemm3).
__global__ __launch_bounds__(256, 4)
void gemm2d_kernel(const unsigned char* __restrict__ s1pack,
                   const _Float16* __restrict__ w2d1,
                   const _Float16* __restrict__ w2d2, const _Float16* __restrict__ w2d3,
                   const float* __restrict__ b2, float* __restrict__ v2,
                   unsigned char* __restrict__ s2b, int t,
                   unsigned* __restrict__ wcnt, unsigned* __restrict__ wlist) {
  constexpr int K = Hd;
  __shared__ __align__(16) unsigned char lAb[128 * 32];
  __shared__ _Float16 lB1[64 * 32], lB2[64 * 32], lB3[64 * 32];
  const int tid = threadIdx.x;
  const int m0 = blockIdx.x * 128, n0 = blockIdx.y * 64;
  const int wave = tid >> 6, lane = tid & 63, l15 = lane & 15, quad = lane >> 4;
  f32x4 acc[2][4][3] = {};
  for (int k0 = 0; k0 < K; k0 += 32) {
    __syncthreads();
    {
      int arow = tid >> 1, akc = (tid & 1) << 4;
      gload_lds16(s1pack + (size_t)(m0 + arow) * Hd + k0 + akc, lAb + arow * 32 + akc);
      size_t tb = ((size_t)blockIdx.y * (K / 32) + (k0 >> 5)) * 2048 + (size_t)tid * 8;
      gload_lds16(w2d1 + tb, lB1 + tid * 8);
      gload_lds16(w2d2 + tb, lB2 + tid * 8);
      gload_lds16(w2d3 + tb, lB3 + tid * 8);
    }
    __syncthreads();
    f16x8 af[2], bf[4][3];
#pragma unroll
    for (int i = 0; i < 2; ++i)
      af[i] = frag_from_bits(lAb + (wave * 32 + i * 16 + l15) * 32 + quad * 8, t);
#pragma unroll
    for (int j = 0; j < 4; ++j) {
      int off = j * 512 + lane * 8;           // fragment order: conflict-free
      bf[j][0] = *(const f16x8*)(lB1 + off);
      bf[j][1] = *(const f16x8*)(lB2 + off);
      bf[j][2] = *(const f16x8*)(lB3 + off);
    }
#pragma unroll
    for (int i = 0; i < 2; ++i)
#pragma unroll
      for (int j = 0; j < 4; ++j)
#pragma unroll
        for (int d = 0; d < 3; ++d)
          acc[i][j][d] = __builtin_amdgcn_mfma_f32_16x16x32_f16(af[i], bf[j][d], acc[i][j][d], 0, 0, 0);
  }
#pragma unroll
  for (int i = 0; i < 2; ++i)
#pragma unroll
    for (int j = 0; j < 4; ++j) {
      int n = n0 + j * 16 + l15;
      float bb = b2[n];
#pragma unroll
      for (int r = 0; r < 4; ++r) {
        int m = m0 + wave * 32 + i * 16 + quad * 4 + r;
        size_t idx = (size_t)m * Hd + n;
        double ge = (double)acc[i][j][0][r]
                  + (double)acc[i][j][1][r] * (1.0 / 4096.0)
                  + (double)acc[i][j][2][r] * (1.0 / 16777216.0);
        float G = (float)ge;                       // cr-fp32 of exact gemm
        float vp = (t == 0) ? 0.0f : v2[idx];
        float h = __fadd_rn(__fadd_rn(vp, G), bb); // np: (v2 + G) + b2
        if (__builtin_fabsf(h - 1.0f) < DELTA) {   // rare: defer to fixup
          unsigned pos = atomicAdd(wcnt, 1u);
          if (pos < WCAP) wlist[pos] = (unsigned)idx;
        }
        bool sp = (h >= 1.0f);
        v2[idx] = sp ? 0.0f : h;
        s2b[(size_t)t * (Bsz * (size_t)Hd) + idx] = sp ? 1 : 0;
      }
    }
}

// ---- fixup: replay np's v2 recursion for worklist sites (3 lanes/site, one
// per KC block; branchless ascending adds; np fold (S1+S2)+S3) — R11-validated.
__global__ __launch_bounds__(256)
void fixup_kernel(const unsigned* __restrict__ wcnt, const unsigned* __restrict__ wlist,
                  const unsigned char* __restrict__ s1pack, const float* __restrict__ w2tf,
                  const float* __restrict__ b2, float* __restrict__ v2,
                  unsigned char* __restrict__ s2b, int t) {
  unsigned cnt = *wcnt;
  if (cnt > WCAP) cnt = WCAP;
  const int tid = threadIdx.x;
  const int lane = tid & 63;
  const int sl = lane / 3, blk3 = lane - sl * 3;
  const int wid = blockIdx.x * (blockDim.x >> 6) + (tid >> 6);
  const int nwaves = gridDim.x * (blockDim.x >> 6);
  for (unsigned base = (unsigned)wid * 21u; base < cnt; base += (unsigned)nwaves * 21u) {
    unsigned site = base + (unsigned)sl;
    bool act = (sl < 21) && (site < cnt);
    unsigned idx = act ? wlist[site] : 0u;
    int m = (int)(idx >> 10), n = (int)(idx & 1023u);
    const unsigned char* prow = s1pack + ((size_t)m << 10);
    const float* col = w2tf + ((size_t)n << 10);
    int kb = blk3 * KC;
    int kend = (blk3 == 2) ? Hd : kb + KC;
    float S[8] = {};
    if (act) {
      for (int k = kb; k < kend; k += 8) {
        float4 wa = *(const float4*)(col + k);
        float4 wb = *(const float4*)(col + k + 4);
        unsigned b0 = *(const unsigned*)(prow + k);
        unsigned b1 = *(const unsigned*)(prow + k + 4);
#pragma unroll
        for (int tau = 0; tau < 8; ++tau) {
          S[tau] = __fadd_rn(S[tau], ((b0 >> tau) & 1)        ? wa.x : 0.0f);
          S[tau] = __fadd_rn(S[tau], ((b0 >> (8 + tau)) & 1)  ? wa.y : 0.0f);
          S[tau] = __fadd_rn(S[tau], ((b0 >> (16 + tau)) & 1) ? wa.z : 0.0f);
          S[tau] = __fadd_rn(S[tau], ((b0 >> (24 + tau)) & 1) ? wa.w : 0.0f);
          S[tau] = __fadd_rn(S[tau], ((b1 >> tau) & 1)        ? wb.x : 0.0f);
          S[tau] = __fadd_rn(S[tau], ((b1 >> (8 + tau)) & 1)  ? wb.y : 0.0f);
          S[tau] = __fadd_rn(S[tau], ((b1 >> (16 + tau)) & 1) ? wb.z : 0.0f);
          S[tau] = __fadd_rn(S[tau], ((b1 >> (24 + tau)) & 1) ? wb.w : 0.0f);
        }
      }
    }
    float G[8];
#pragma unroll
    for (int tau = 0; tau < 8; ++tau) {
      float sB = __shfl(S[tau], lane + 1);
      float sC = __shfl(S[tau], lane + 2);
      G[tau] = __fadd_rn(__fadd_rn(S[tau], sB), sC);
    }
    if (act && blk3 == 0) {
      float bb = b2[n];
      float v = 0.0f;
      bool sp = false;
      for (int tau = 0; tau <= t; ++tau) {
        float h = __fadd_rn(__fadd_rn(v, G[tau]), bb);
        sp = (h >= 1.0f);
        v = sp ? 0.0f : h;
      }
      v2[idx] = v;
      s2b[(size_t)t * (Bsz * (size_t)Hd) + idx] = sp ? 1 : 0;
    }
  }
}

// ---- batched GEMM3 over all 8 steps (flat M = 8*8192): G3 = cr-fp32 of
// exact s2@w3 per (t,m,n) — same per-cell accumulation order as before.
__global__ __launch_bounds__(256, 4)
void gemm3b_kernel(const unsigned char* __restrict__ s2b,
                   const _Float16* __restrict__ w3d1, const _Float16* __restrict__ w3d2,
                   const _Float16* __restrict__ w3d3, float* __restrict__ g3) {
  constexpr int K = Hd;
  __shared__ __align__(16) unsigned char lAb[64 * 32];
  __shared__ _Float16 lB1[64 * 32], lB2[64 * 32], lB3[64 * 32];
  const int tid = threadIdx.x;
  const size_t row0 = (size_t)blockIdx.x * 64;     // flat rows (t*8192 + m)
  const int wave = tid >> 6, lane = tid & 63, l15 = lane & 15, quad = lane >> 4;
  f32x4 acc[4][3] = {};
  for (int k0 = 0; k0 < K; k0 += 32) {
    __syncthreads();
    if (tid < 128) {
      int arow = tid >> 1, akc = (tid & 1) << 4;
      gload_lds16(s2b + (row0 + arow) * Hd + k0 + akc, lAb + arow * 32 + akc);
    }
    {
      size_t tb = (size_t)(k0 >> 5) * 2048 + (size_t)tid * 8;
      gload_lds16(w3d1 + tb, lB1 + tid * 8);
      gload_lds16(w3d2 + tb, lB2 + tid * 8);
      gload_lds16(w3d3 + tb, lB3 + tid * 8);
    }
    __syncthreads();
    f16x8 af = frag_from_bytes(lAb + (wave * 16 + l15) * 32 + quad * 8);
    f16x8 bf[4][3];
#pragma unroll
    for (int j = 0; j < 4; ++j) {
      int off = j * 512 + lane * 8;               // fragment order: conflict-free
      bf[j][0] = *(const f16x8*)(lB1 + off);
      bf[j][1] = *(const f16x8*)(lB2 + off);
      bf[j][2] = *(const f16x8*)(lB3 + off);
    }
#pragma unroll
    for (int j = 0; j < 4; ++j)
#pragma unroll
      for (int d = 0; d < 3; ++d)
        acc[j][d] = __builtin_amdgcn_mfma_f32_16x16x32_f16(af, bf[j][d], acc[j][d], 0, 0, 0);
  }
#pragma unroll
  for (int j = 0; j < 4; ++j) {
    int n = j * 16 + l15;
#pragma unroll
    for (int r = 0; r < 4; ++r) {
      size_t row = row0 + wave * 16 + quad * 4 + r;
      double ge = (double)acc[j][0][r]
                + (double)acc[j][1][r] * (1.0 / 4096.0)
                + (double)acc[j][2][r] * (1.0 / 16777216.0);
      g3[row * Od + n] = (float)ge;
    }
  }
}

// ---- v3 LIF recurrence over t (same fp32 op order as before)
__global__ void v3rec_kernel(const float* __restrict__ g3, const float* __restrict__ b3,
                             float* __restrict__ v3) {
  int idx = blockIdx.x * 256 + threadIdx.x;        // over Bsz*Od
  float bb = b3[idx & (Od - 1)];
  float v = 0.0f;
#pragma unroll
  for (int t = 0; t < 8; ++t) {
    float x3 = __fadd_rn(g3[(size_t)t * (Bsz * Od) + idx], bb);
    float d  = __fsub_rn(x3, v);
    v = __fadd_rn(v, __fmul_rn(d, 0.5f));
  }
  v3[idx] = v;
}

// ---- final: fp32 op sequence as numpy; tanh clamped at |z| >= 7.90531111
// (R8-validated: np's tanh is exactly +/-1 on all live band coords)
__global__ void final_kernel(const float* __restrict__ v3, const float* __restrict__ eps,
                             float* __restrict__ action, float* __restrict__ logp) {
  int tid = threadIdx.x;
  int row = blockIdx.x * 8 + (tid >> 5);
  int j = tid & 31;
  float mu = v3[(size_t)row * Od + j];
  float ls = v3[(size_t)row * Od + 32 + j];
  ls = fminf(fmaxf(ls, -20.0f), 2.0f);
  float sd = (float)exp((double)ls);
  float e  = eps[(size_t)row * Aact + j];
  float z  = __fadd_rn(mu, __fmul_rn(sd, e));
  float a;
  if (__builtin_fabsf(z) >= 7.90531111f) a = __builtin_copysignf(1.0f, z);
  else                                   a = (float)tanh((double)z);
  float aa = __fmul_rn(a, a);
  float u  = __fadd_rn(__fsub_rn(1.0f, aa), 1e-7f);
  float lg = (float)log((double)u);
  float l  = __fmul_rn(__fmul_rn(-0.5f, e), e);
  l = __fsub_rn(l, ls);
  l = __fsub_rn(l, 0.9189385332046727f);
  float term = __fsub_rn(l, lg);
  action[(size_t)row * Aact + j] = a;
  double lp = (double)term;
#pragma unroll
  for (int w = 16; w >= 1; w >>= 1) lp += __shfl_xor(lp, w);
  if (j == 0) logp[row] = (float)lp;
}

extern "C" void kernel_launch(void* const* d_in, const int* in_sizes, int n_in,
                              void* d_out, int out_size, void* d_ws, size_t ws_size,
                              hipStream_t stream) {
  const float* state = (const float*)d_in[0];
  const float* w1 = (const float*)d_in[1];
  const float* b1 = (const float*)d_in[2];
  const float* w2 = (const float*)d_in[3];
  const float* b2 = (const float*)d_in[4];
  const float* w3 = (const float*)d_in[5];
  const float* b3 = (const float*)d_in[6];
  const float* eps = (const float*)d_in[7];
  float* out_action = (float*)d_out;
  float* out_logp = out_action + (size_t)Bsz * Aact;

  char* p = (char*)d_ws;
  auto take = [&](size_t bytes) {
    char* r = p;
    p += (bytes + 255) & ~(size_t)255;
    return r;
  };
  float* v2f = (float*)take((size_t)Bsz * Hd * 4);                 // 32 MB
  float* v3f = (float*)take((size_t)Bsz * Od * 4);                 // 2 MB
  unsigned char* s1pack = (unsigned char*)take((size_t)Bsz * Hd);  // 8 MB
  unsigned char* s2b = (unsigned char*)take((size_t)Bsz * Hd * 8); // 64 MB
  float* g3 = (float*)take((size_t)Bsz * Od * 8 * 4);              // 16 MB
  _Float16* w2p1 = (_Float16*)take((size_t)Hd * Hd * 2);
  _Float16* w2p2 = (_Float16*)take((size_t)Hd * Hd * 2);
  _Float16* w2p3 = (_Float16*)take((size_t)Hd * Hd * 2);
  _Float16* w3p1 = (_Float16*)take((size_t)Od * Hd * 2);
  _Float16* w3p2 = (_Float16*)take((size_t)Od * Hd * 2);
  _Float16* w3p3 = (_Float16*)take((size_t)Od * Hd * 2);
  float* w2tf = (float*)take((size_t)Hd * Hd * 4);                 // 4 MB
  unsigned* wcnt = (unsigned*)take(8 * 4);
  unsigned* wlist = (unsigned*)take((size_t)WCAP * 4);             // 256 KB

  wsplit_tiled_kernel<<<dim3(Hd / 64, Hd / 32), 256, 0, stream>>>(w2, w2p1, w2p2, w2p3, Hd, Hd);
  wsplit_tiled_kernel<<<dim3(Od / 64, Hd / 32), 256, 0, stream>>>(w3, w3p1, w3p2, w3p3, Od, Hd);
  transpose_f32_kernel<<<dim3(Hd / 32, Hd / 32), dim3(32, 8), 0, stream>>>(w2, w2tf, Hd, Hd);
  x1_kernel<<<dim3(Bsz / 64, Hd / 32), 256, 0, stream>>>(state, w1, b1, s1pack);
  hipMemsetAsync(wcnt, 0, 8 * 4, stream);

  for (int t = 0; t < 8; ++t) {
    gemm2d_kernel<<<dim3(Bsz / 128, Hd / 64), 256, 0, stream>>>(s1pack, w2p1, w2p2, w2p3,
                                                                b2, v2f, s2b, t,
                                                                wcnt + t, wlist);
    fixup_kernel<<<32, 256, 0, stream>>>(wcnt + t, wlist, s1pack, w2tf, b2, v2f, s2b, t);
  }

  gemm3b_kernel<<<(8 * Bsz) / 64, 256, 0, stream>>>(s2b, w3p1, w3p2, w3p3, g3);
  v3rec_kernel<<<(Bsz * Od) / 256, 256, 0, stream>>>(g3, b3, v3f);
  final_kernel<<<Bsz / 8, 256, 0, stream>>>(v3f, eps, out_action, out_logp);
}

// Round 14
// 1086.471 us; speedup vs baseline: 3.4026x; 3.4026x over previous
//
#include <hip/hip_runtime.h>

typedef _Float16 f16x8 __attribute__((ext_vector_type(8)));
typedef _Float16 f16x4 __attribute__((ext_vector_type(4)));
typedef float    f32x4 __attribute__((ext_vector_type(4)));

typedef const __attribute__((address_space(1))) void* gptr_t;
typedef __attribute__((address_space(3))) void* lptr_t;

__device__ __forceinline__ void gload_lds16(const void* g, void* l) {
  __builtin_amdgcn_global_load_lds((gptr_t)g, (lptr_t)l, 16, 0, 0);
}

constexpr int Bsz  = 8192;
constexpr int Nin  = 128;
constexpr int Hd   = 1024;
constexpr int Aact = 32;
constexpr int Od   = 64;
constexpr int KC = 384;           // OpenBLAS K-block (R10-validated)
constexpr float DELTA = 2e-5f;    // borderline window (R10-validated)
constexpr unsigned WCAP = 65536;

// ---- digit split + swizzle into MFMA B-fragment order (R13-validated layout).
__global__ void wsplit_tiled_kernel(const float* __restrict__ src,  // [k][n] row-major
                                    _Float16* __restrict__ d1, _Float16* __restrict__ d2,
                                    _Float16* __restrict__ d3, int N, int K) {
  const int tid = threadIdx.x;
  const int j = tid >> 6, lane = tid & 63, l15 = lane & 15, quad = lane >> 4;
  const int n = blockIdx.x * 64 + j * 16 + l15;
  const int kb = blockIdx.y;
  const int k0 = kb * 32 + quad * 8;
  f16x8 o1, o2, o3;
#pragma unroll
  for (int e = 0; e < 8; ++e) {
    float w = src[(size_t)(k0 + e) * N + n];
    float m1 = rintf(w * 2048.0f);
    float q1 = m1 * (1.0f / 2048.0f);
    float r  = w - q1;                       // exact
    float m2 = rintf(r * 8388608.0f);        // 2^23
    float q2 = m2 * (1.0f / 8388608.0f);
    float r2 = r - q2;                       // exact
    float m3 = rintf(r2 * 34359738368.0f);   // 2^35
    o1[e] = (_Float16)q1;
    o2[e] = (_Float16)(m2 * (1.0f / 2048.0f));
    o3[e] = (_Float16)(m3 * (1.0f / 2048.0f));
  }
  size_t off = ((size_t)blockIdx.x * (K / 32) + kb) * 2048 + (j * 64 + lane) * 8;
  *(f16x8*)(d1 + off) = o1;
  *(f16x8*)(d2 + off) = o2;
  *(f16x8*)(d3 + off) = o3;
}

// ---- fp32 transpose: src[R][C] -> dst[C][R] (fixup column contiguity)
__global__ void transpose_f32_kernel(const float* __restrict__ src,
                                     float* __restrict__ dst, int R, int C) {
  __shared__ float tile[32][33];
  int c0 = blockIdx.x * 32, r0 = blockIdx.y * 32;
  for (int i = threadIdx.y; i < 32; i += 8)
    tile[i][threadIdx.x] = src[(size_t)(r0 + i) * C + c0 + threadIdx.x];
  __syncthreads();
  for (int i = threadIdx.y; i < 32; i += 8)
    dst[(size_t)(c0 + i) * R + r0 + threadIdx.x] = tile[threadIdx.x][i];
}

// ---- layer 1: EMULATE np's sgemm (K=128 single block, ascending fp32 FMA),
// then the fp32 trajectory; v resets to exact 0 -> pack 8 steps' spikes/byte.
__global__ __launch_bounds__(256)
void x1_kernel(const float* __restrict__ state, const float* __restrict__ w1,
               const float* __restrict__ b1, unsigned char* __restrict__ s1pack) {
  __shared__ float sA[64][129];
  __shared__ float sB[128][32];
  const int m0 = blockIdx.x * 64, n0 = blockIdx.y * 32;
  const int tid = threadIdx.x;
  for (int idx = tid; idx < 64 * 32; idx += 256) {
    int r = idx >> 5, c4 = (idx & 31) << 2;
    float4 v = *(const float4*)(state + (size_t)(m0 + r) * Nin + c4);
    sA[r][c4] = v.x; sA[r][c4 + 1] = v.y; sA[r][c4 + 2] = v.z; sA[r][c4 + 3] = v.w;
  }
  for (int idx = tid; idx < 128 * 8; idx += 256) {
    int r = idx >> 3, c4 = (idx & 7) << 2;
    *(float4*)&sB[r][c4] = *(const float4*)(w1 + (size_t)r * Hd + n0 + c4);
  }
  __syncthreads();
  const int tx = tid & 15, ty = tid >> 4;
  float acc[4][2] = {};
  for (int k = 0; k < 128; ++k) {           // ASCENDING, single acc: np order
    float a[4], b[2];
#pragma unroll
    for (int i = 0; i < 4; ++i) a[i] = sA[ty * 4 + i][k];
#pragma unroll
    for (int j = 0; j < 2; ++j) b[j] = sB[k][tx * 2 + j];
#pragma unroll
    for (int i = 0; i < 4; ++i)
#pragma unroll
      for (int j = 0; j < 2; ++j) acc[i][j] = __fmaf_rn(a[i], b[j], acc[i][j]);
  }
#pragma unroll
  for (int i = 0; i < 4; ++i)
#pragma unroll
    for (int j = 0; j < 2; ++j) {
      int m = m0 + ty * 4 + i, n = n0 + tx * 2 + j;
      float x = acc[i][j];
      float bb = b1[n];
      float v = 0.0f;
      unsigned bits = 0;
#pragma unroll
      for (int t = 0; t < 8; ++t) {
        float h = __fadd_rn(__fadd_rn(v, x), bb);   // np: (v1 + G1) + b1
        if (h >= 1.0f) { bits |= (1u << t); v = 0.0f; } else { v = h; }
      }
      s1pack[(size_t)m * Hd + n] = (unsigned char)bits;
    }
}

// f16 A-fragment from 8 spike bytes (bit t) — values identical to f16 expand.
__device__ __forceinline__ f16x8 frag_from_bits(const unsigned char* ap, int t) {
  unsigned d0 = *(const unsigned*)ap;
  unsigned d1 = *(const unsigned*)(ap + 4);
  f16x8 a;
  a[0] = (_Float16)((d0 >> t) & 1u);
  a[1] = (_Float16)((d0 >> (8 + t)) & 1u);
  a[2] = (_Float16)((d0 >> (16 + t)) & 1u);
  a[3] = (_Float16)((d0 >> (24 + t)) & 1u);
  a[4] = (_Float16)((d1 >> t) & 1u);
  a[5] = (_Float16)((d1 >> (8 + t)) & 1u);
  a[6] = (_Float16)((d1 >> (16 + t)) & 1u);
  a[7] = (_Float16)((d1 >> (24 + t)) & 1u);
  return a;
}

// f16 A-fragment from 8 s2 bytes (each 0 or 1)
__device__ __forceinline__ f16x8 frag_from_bytes(const unsigned char* ap) {
  f16x8 a;
#pragma unroll
  for (int e = 0; e < 8; ++e) a[e] = (_Float16)(float)ap[e];
  return a;
}

// ---- GEMM2: exact 3-digit MFMA decides non-borderline spikes (== np);
// borderline -> worklist for fixup. B in fragment-order tiles (conflict-free).
// launch_bounds (256,2): at 4 blocks/CU all 16 n-columns are co-resident per
// XCD -> 6 MB B working set > 4 MB L2 -> thrash (R13: FETCH 49->771 MB,
// gemm2d 89->410 us). 2/CU keeps 8 columns = 3 MB resident: fits.
__global__ __launch_bounds__(256, 2)
void gemm2d_kernel(const unsigned char* __restrict__ s1pack,
                   const _Float16* __restrict__ w2d1,
                   const _Float16* __restrict__ w2d2, const _Float16* __restrict__ w2d3,
                   const float* __restrict__ b2, float* __restrict__ v2,
                   unsigned char* __restrict__ s2b, int t,
                   unsigned* __restrict__ wcnt, unsigned* __restrict__ wlist) {
  constexpr int K = Hd;
  __shared__ __align__(16) unsigned char lAb[128 * 32];
  __shared__ _Float16 lB1[64 * 32], lB2[64 * 32], lB3[64 * 32];
  const int tid = threadIdx.x;
  const int m0 = blockIdx.x * 128, n0 = blockIdx.y * 64;
  const int wave = tid >> 6, lane = tid & 63, l15 = lane & 15, quad = lane >> 4;
  f32x4 acc[2][4][3] = {};
  for (int k0 = 0; k0 < K; k0 += 32) {
    __syncthreads();
    {
      int arow = tid >> 1, akc = (tid & 1) << 4;
      gload_lds16(s1pack + (size_t)(m0 + arow) * Hd + k0 + akc, lAb + arow * 32 + akc);
      size_t tb = ((size_t)blockIdx.y * (K / 32) + (k0 >> 5)) * 2048 + (size_t)tid * 8;
      gload_lds16(w2d1 + tb, lB1 + tid * 8);
      gload_lds16(w2d2 + tb, lB2 + tid * 8);
      gload_lds16(w2d3 + tb, lB3 + tid * 8);
    }
    __syncthreads();
    f16x8 af[2], bf[4][3];
#pragma unroll
    for (int i = 0; i < 2; ++i)
      af[i] = frag_from_bits(lAb + (wave * 32 + i * 16 + l15) * 32 + quad * 8, t);
#pragma unroll
    for (int j = 0; j < 4; ++j) {
      int off = j * 512 + lane * 8;           // fragment order: conflict-free
      bf[j][0] = *(const f16x8*)(lB1 + off);
      bf[j][1] = *(const f16x8*)(lB2 + off);
      bf[j][2] = *(const f16x8*)(lB3 + off);
    }
#pragma unroll
    for (int i = 0; i < 2; ++i)
#pragma unroll
      for (int j = 0; j < 4; ++j)
#pragma unroll
        for (int d = 0; d < 3; ++d)
          acc[i][j][d] = __builtin_amdgcn_mfma_f32_16x16x32_f16(af[i], bf[j][d], acc[i][j][d], 0, 0, 0);
  }
#pragma unroll
  for (int i = 0; i < 2; ++i)
#pragma unroll
    for (int j = 0; j < 4; ++j) {
      int n = n0 + j * 16 + l15;
      float bb = b2[n];
#pragma unroll
      for (int r = 0; r < 4; ++r) {
        int m = m0 + wave * 32 + i * 16 + quad * 4 + r;
        size_t idx = (size_t)m * Hd + n;
        double ge = (double)acc[i][j][0][r]
                  + (double)acc[i][j][1][r] * (1.0 / 4096.0)
                  + (double)acc[i][j][2][r] * (1.0 / 16777216.0);
        float G = (float)ge;                       // cr-fp32 of exact gemm
        float vp = (t == 0) ? 0.0f : v2[idx];
        float h = __fadd_rn(__fadd_rn(vp, G), bb); // np: (v2 + G) + b2
        if (__builtin_fabsf(h - 1.0f) < DELTA) {   // rare: defer to fixup
          unsigned pos = atomicAdd(wcnt, 1u);
          if (pos < WCAP) wlist[pos] = (unsigned)idx;
        }
        bool sp = (h >= 1.0f);
        v2[idx] = sp ? 0.0f : h;
        s2b[(size_t)t * (Bsz * (size_t)Hd) + idx] = sp ? 1 : 0;
      }
    }
}

// ---- fixup: replay np's v2 recursion for worklist sites (3 lanes/site, one
// per KC block; branchless ascending adds; np fold (S1+S2)+S3) — R11-validated.
__global__ __launch_bounds__(256)
void fixup_kernel(const unsigned* __restrict__ wcnt, const unsigned* __restrict__ wlist,
                  const unsigned char* __restrict__ s1pack, const float* __restrict__ w2tf,
                  const float* __restrict__ b2, float* __restrict__ v2,
                  unsigned char* __restrict__ s2b, int t) {
  unsigned cnt = *wcnt;
  if (cnt > WCAP) cnt = WCAP;
  const int tid = threadIdx.x;
  const int lane = tid & 63;
  const int sl = lane / 3, blk3 = lane - sl * 3;
  const int wid = blockIdx.x * (blockDim.x >> 6) + (tid >> 6);
  const int nwaves = gridDim.x * (blockDim.x >> 6);
  for (unsigned base = (unsigned)wid * 21u; base < cnt; base += (unsigned)nwaves * 21u) {
    unsigned site = base + (unsigned)sl;
    bool act = (sl < 21) && (site < cnt);
    unsigned idx = act ? wlist[site] : 0u;
    int m = (int)(idx >> 10), n = (int)(idx & 1023u);
    const unsigned char* prow = s1pack + ((size_t)m << 10);
    const float* col = w2tf + ((size_t)n << 10);
    int kb = blk3 * KC;
    int kend = (blk3 == 2) ? Hd : kb + KC;
    float S[8] = {};
    if (act) {
      for (int k = kb; k < kend; k += 8) {
        float4 wa = *(const float4*)(col + k);
        float4 wb = *(const float4*)(col + k + 4);
        unsigned b0 = *(const unsigned*)(prow + k);
        unsigned b1 = *(const unsigned*)(prow + k + 4);
#pragma unroll
        for (int tau = 0; tau < 8; ++tau) {
          S[tau] = __fadd_rn(S[tau], ((b0 >> tau) & 1)        ? wa.x : 0.0f);
          S[tau] = __fadd_rn(S[tau], ((b0 >> (8 + tau)) & 1)  ? wa.y : 0.0f);
          S[tau] = __fadd_rn(S[tau], ((b0 >> (16 + tau)) & 1) ? wa.z : 0.0f);
          S[tau] = __fadd_rn(S[tau], ((b0 >> (24 + tau)) & 1) ? wa.w : 0.0f);
          S[tau] = __fadd_rn(S[tau], ((b1 >> tau) & 1)        ? wb.x : 0.0f);
          S[tau] = __fadd_rn(S[tau], ((b1 >> (8 + tau)) & 1)  ? wb.y : 0.0f);
          S[tau] = __fadd_rn(S[tau], ((b1 >> (16 + tau)) & 1) ? wb.z : 0.0f);
          S[tau] = __fadd_rn(S[tau], ((b1 >> (24 + tau)) & 1) ? wb.w : 0.0f);
        }
      }
    }
    float G[8];
#pragma unroll
    for (int tau = 0; tau < 8; ++tau) {
      float sB = __shfl(S[tau], lane + 1);
      float sC = __shfl(S[tau], lane + 2);
      G[tau] = __fadd_rn(__fadd_rn(S[tau], sB), sC);
    }
    if (act && blk3 == 0) {
      float bb = b2[n];
      float v = 0.0f;
      bool sp = false;
      for (int tau = 0; tau <= t; ++tau) {
        float h = __fadd_rn(__fadd_rn(v, G[tau]), bb);
        sp = (h >= 1.0f);
        v = sp ? 0.0f : h;
      }
      v2[idx] = v;
      s2b[(size_t)t * (Bsz * (size_t)Hd) + idx] = sp ? 1 : 0;
    }
  }
}

// ---- batched GEMM3 over all 8 steps (flat M = 8*8192). Single shared 384 KB
// B column -> 4 blocks/CU is L2-safe here.
__global__ __launch_bounds__(256, 4)
void gemm3b_kernel(const unsigned char* __restrict__ s2b,
                   const _Float16* __restrict__ w3d1, const _Float16* __restrict__ w3d2,
                   const _Float16* __restrict__ w3d3, float* __restrict__ g3) {
  constexpr int K = Hd;
  __shared__ __align__(16) unsigned char lAb[64 * 32];
  __shared__ _Float16 lB1[64 * 32], lB2[64 * 32], lB3[64 * 32];
  const int tid = threadIdx.x;
  const size_t row0 = (size_t)blockIdx.x * 64;     // flat rows (t*8192 + m)
  const int wave = tid >> 6, lane = tid & 63, l15 = lane & 15, quad = lane >> 4;
  f32x4 acc[4][3] = {};
  for (int k0 = 0; k0 < K; k0 += 32) {
    __syncthreads();
    if (tid < 128) {
      int arow = tid >> 1, akc = (tid & 1) << 4;
      gload_lds16(s2b + (row0 + arow) * Hd + k0 + akc, lAb + arow * 32 + akc);
    }
    {
      size_t tb = (size_t)(k0 >> 5) * 2048 + (size_t)tid * 8;
      gload_lds16(w3d1 + tb, lB1 + tid * 8);
      gload_lds16(w3d2 + tb, lB2 + tid * 8);
      gload_lds16(w3d3 + tb, lB3 + tid * 8);
    }
    __syncthreads();
    f16x8 af = frag_from_bytes(lAb + (wave * 16 + l15) * 32 + quad * 8);
    f16x8 bf[4][3];
#pragma unroll
    for (int j = 0; j < 4; ++j) {
      int off = j * 512 + lane * 8;               // fragment order: conflict-free
      bf[j][0] = *(const f16x8*)(lB1 + off);
      bf[j][1] = *(const f16x8*)(lB2 + off);
      bf[j][2] = *(const f16x8*)(lB3 + off);
    }
#pragma unroll
    for (int j = 0; j < 4; ++j)
#pragma unroll
      for (int d = 0; d < 3; ++d)
        acc[j][d] = __builtin_amdgcn_mfma_f32_16x16x32_f16(af, bf[j][d], acc[j][d], 0, 0, 0);
  }
#pragma unroll
  for (int j = 0; j < 4; ++j) {
    int n = j * 16 + l15;
#pragma unroll
    for (int r = 0; r < 4; ++r) {
      size_t row = row0 + wave * 16 + quad * 4 + r;
      double ge = (double)acc[j][0][r]
                + (double)acc[j][1][r] * (1.0 / 4096.0)
                + (double)acc[j][2][r] * (1.0 / 16777216.0);
      g3[row * Od + n] = (float)ge;
    }
  }
}

// ---- v3 LIF recurrence over t (same fp32 op order as before)
__global__ void v3rec_kernel(const float* __restrict__ g3, const float* __restrict__ b3,
                             float* __restrict__ v3) {
  int idx = blockIdx.x * 256 + threadIdx.x;        // over Bsz*Od
  float bb = b3[idx & (Od - 1)];
  float v = 0.0f;
#pragma unroll
  for (int t = 0; t < 8; ++t) {
    float x3 = __fadd_rn(g3[(size_t)t * (Bsz * Od) + idx], bb);
    float d  = __fsub_rn(x3, v);
    v = __fadd_rn(v, __fmul_rn(d, 0.5f));
  }
  v3[idx] = v;
}

// ---- final: fp32 op sequence as numpy; tanh clamped at |z| >= 7.90531111
// (R8-validated: np's tanh is exactly +/-1 on all live band coords)
__global__ void final_kernel(const float* __restrict__ v3, const float* __restrict__ eps,
                             float* __restrict__ action, float* __restrict__ logp) {
  int tid = threadIdx.x;
  int row = blockIdx.x * 8 + (tid >> 5);
  int j = tid & 31;
  float mu = v3[(size_t)row * Od + j];
  float ls = v3[(size_t)row * Od + 32 + j];
  ls = fminf(fmaxf(ls, -20.0f), 2.0f);
  float sd = (float)exp((double)ls);
  float e  = eps[(size_t)row * Aact + j];
  float z  = __fadd_rn(mu, __fmul_rn(sd, e));
  float a;
  if (__builtin_fabsf(z) >= 7.90531111f) a = __builtin_copysignf(1.0f, z);
  else                                   a = (float)tanh((double)z);
  float aa = __fmul_rn(a, a);
  float u  = __fadd_rn(__fsub_rn(1.0f, aa), 1e-7f);
  float lg = (float)log((double)u);
  float l  = __fmul_rn(__fmul_rn(-0.5f, e), e);
  l = __fsub_rn(l, ls);
  l = __fsub_rn(l, 0.9189385332046727f);
  float term = __fsub_rn(l, lg);
  action[(size_t)row * Aact + j] = a;
  double lp = (double)term;
#pragma unroll
  for (int w = 16; w >= 1; w >>= 1) lp += __shfl_xor(lp, w);
  if (j == 0) logp[row] = (float)lp;
}

extern "C" void kernel_launch(void* const* d_in, const int* in_sizes, int n_in,
                              void* d_out, int out_size, void* d_ws, size_t ws_size,
                              hipStream_t stream) {
  const float* state = (const float*)d_in[0];
  const float* w1 = (const float*)d_in[1];
  const float* b1 = (const float*)d_in[2];
  const float* w2 = (const float*)d_in[3];
  const float* b2 = (const float*)d_in[4];
  const float* w3 = (const float*)d_in[5];
  const float* b3 = (const float*)d_in[6];
  const float* eps = (const float*)d_in[7];
  float* out_action = (float*)d_out;
  float* out_logp = out_action + (size_t)Bsz * Aact;

  char* p = (char*)d_ws;
  auto take = [&](size_t bytes) {
    char* r = p;
    p += (bytes + 255) & ~(size_t)255;
    return r;
  };
  float* v2f = (float*)take((size_t)Bsz * Hd * 4);                 // 32 MB
  float* v3f = (float*)take((size_t)Bsz * Od * 4);                 // 2 MB
  unsigned char* s1pack = (unsigned char*)take((size_t)Bsz * Hd);  // 8 MB
  unsigned char* s2b = (unsigned char*)take((size_t)Bsz * Hd * 8); // 64 MB
  float* g3 = (float*)take((size_t)Bsz * Od * 8 * 4);              // 16 MB
  _Float16* w2p1 = (_Float16*)take((size_t)Hd * Hd * 2);
  _Float16* w2p2 = (_Float16*)take((size_t)Hd * Hd * 2);
  _Float16* w2p3 = (_Float16*)take((size_t)Hd * Hd * 2);
  _Float16* w3p1 = (_Float16*)take((size_t)Od * Hd * 2);
  _Float16* w3p2 = (_Float16*)take((size_t)Od * Hd * 2);
  _Float16* w3p3 = (_Float16*)take((size_t)Od * Hd * 2);
  float* w2tf = (float*)take((size_t)Hd * Hd * 4);                 // 4 MB
  unsigned* wcnt = (unsigned*)take(8 * 4);
  unsigned* wlist = (unsigned*)take((size_t)WCAP * 4);             // 256 KB

  wsplit_tiled_kernel<<<dim3(Hd / 64, Hd / 32), 256, 0, stream>>>(w2, w2p1, w2p2, w2p3, Hd, Hd);
  wsplit_tiled_kernel<<<dim3(Od / 64, Hd / 32), 256, 0, stream>>>(w3, w3p1, w3p2, w3p3, Od, Hd);
  transpose_f32_kernel<<<dim3(Hd / 32, Hd / 32), dim3(32, 8), 0, stream>>>(w2, w2tf, Hd, Hd);
  x1_kernel<<<dim3(Bsz / 64, Hd / 32), 256, 0, stream>>>(state, w1, b1, s1pack);
  hipMemsetAsync(wcnt, 0, 8 * 4, stream);

  for (int t = 0; t < 8; ++t) {
    gemm2d_kernel<<<dim3(Bsz / 128, Hd / 64), 256, 0, stream>>>(s1pack, w2p1, w2p2, w2p3,
                                                                b2, v2f, s2b, t,
                                                                wcnt + t, wlist);
    fixup_kernel<<<32, 256, 0, stream>>>(wcnt + t, wlist, s1pack, w2tf, b2, v2f, s2b, t);
  }

  gemm3b_kernel<<<(8 * Bsz) / 64, 256, 0, stream>>>(s2b, w3p1, w3p2, w3p3, g3);
  v3rec_kernel<<<(Bsz * Od) / 256, 256, 0, stream>>>(g3, b3, v3f);
  final_kernel<<<Bsz / 8, 256, 0, stream>>>(v3f, eps, out_action, out_logp);
}